// Round 13
// baseline (102.990 us; speedup 1.0000x reference)
//
#include <hip/hip_runtime.h>
#include <hip/hip_bf16.h>

typedef __attribute__((ext_vector_type(8))) short bf16x8;
typedef __attribute__((ext_vector_type(4))) float f32x4;
typedef __attribute__((ext_vector_type(4))) unsigned short u16x4;

#define WIDTH  2048
#define NHEADS 16
#define HDIM   128
#define BM     64

__device__ __forceinline__ unsigned short f2bf(float f) {
  union { float f; unsigned int u; } v; v.f = f;
  unsigned int u = v.u;
  unsigned int r = (u + 0x7FFFu + ((u >> 16) & 1u)) >> 16;  // RNE
  return (unsigned short)r;
}

__device__ __forceinline__ float bf2f(unsigned short s) {
  union { unsigned int u; float f; } v;
  v.u = ((unsigned int)s) << 16;
  return v.f;
}

// pack two f32 -> two bf16 (RNE); scalar casts so the compiler can fuse to
// v_cvt_pk_bf16_f32 (m240: do NOT hand-write the asm).
__device__ __forceinline__ unsigned int pk_bf16(float lo, float hi) {
  __hip_bfloat162 b = __float22bfloat162_rn(make_float2(lo, hi));
  union { __hip_bfloat162 b; unsigned int u; } c; c.b = b;
  return c.u;
}

#define LOG2E 1.4426950408889634f

// Prep: transpose w_in/w_a [h][i][j] -> bf16 [h][j][i], PRE-SCALED by log2(e)
// (gate pre-activations in log2 domain). Scaled biases; sp8 = 8*softplus*log2e.
__global__ __launch_bounds__(256) void prep_kernel(
    const float* __restrict__ w_in, const float* __restrict__ w_a,
    const float* __restrict__ a_param,
    const float* __restrict__ b_in, const float* __restrict__ b_a,
    unsigned short* __restrict__ wTin, unsigned short* __restrict__ wTa,
    float* __restrict__ sp8, float* __restrict__ sbi, float* __restrict__ sba) {
  int tid = blockIdx.x * 256 + threadIdx.x;    // 0 .. 16*128*128-1
  int h   = tid >> 14;
  int rem = tid & 16383;
  int j   = rem >> 7;
  int i   = rem & 127;
  int src = (h << 14) + (i << 7) + j;
  wTin[tid] = f2bf(w_in[src] * LOG2E);
  wTa[tid]  = f2bf(w_a[src] * LOG2E);
  if (tid < WIDTH) {
    float v  = a_param[tid];
    float sp = (v > 20.0f) ? v : log1pf(__expf(v));
    sp8[tid] = 8.0f * sp * LOG2E;
    sbi[tid] = b_in[tid] * LOG2E;
    sba[tid] = b_a[tid] * LOG2E;
  }
}

// R12 structure + VALU diet round 2:
//  - staging conversion via hardware v_cvt_pk_bf16_f32 (scalar-cast path)
//  - bias folded into the MFMA accumulator init (adds move to matrix pipe)
__global__ __launch_bounds__(256, 4) void rglru_kernel(
    const float* __restrict__ x, const float* __restrict__ state,
    const float* __restrict__ sbi, const float* __restrict__ sba,
    const unsigned short* __restrict__ wTin, const unsigned short* __restrict__ wTa,
    const float* __restrict__ sp8, float* __restrict__ out) {
  __shared__ unsigned short xs[BM * HDIM];  // bf16 x-tile, XOR-swizzled

  const int bid  = blockIdx.x;
  const int h    = bid & (NHEADS - 1);
  const int rb   = bid >> 4;
  const int t    = threadIdx.x;
  const int lane = t & 63;
  const int wid  = t >> 6;
  const int l15  = lane & 15;
  const int l4   = lane >> 4;

  // ---- stage x tile (BM x HDIM f32 -> bf16 LDS, swizzled) ----
  const float* xtile = x + (long)rb * BM * WIDTH + h * HDIM;
#pragma unroll
  for (int it = 0; it < 8; ++it) {
    int idx = it * 256 + t;            // float4 index within tile (0..2047)
    int r   = idx >> 5;                // row 0..63
    int c4  = idx & 31;                // float4 within row
    f32x4 v = __builtin_nontemporal_load(
        reinterpret_cast<const f32x4*>(xtile + (long)r * WIDTH) + c4);
    uint2 p;
    p.x = pk_bf16(v[0], v[1]);
    p.y = pk_bf16(v[2], v[3]);
    int off = (r * 256 + c4 * 8) ^ ((r & 7) << 4);
    *reinterpret_cast<uint2*>(reinterpret_cast<char*>(xs) + off) = p;
  }

  // per-column constants (needed before MFMA for the bias-in-acc init)
  const int cb = h * HDIM + wid * 32 + l4 * 4;
  f32x4 bi0 = *reinterpret_cast<const f32x4*>(sbi + cb);
  f32x4 bi1 = *reinterpret_cast<const f32x4*>(sbi + cb + 16);
  f32x4 ba0 = *reinterpret_cast<const f32x4*>(sba + cb);
  f32x4 ba1 = *reinterpret_cast<const f32x4*>(sba + cb + 16);
  f32x4 sp0 = *reinterpret_cast<const f32x4*>(sp8 + cb);
  f32x4 sp1 = *reinterpret_cast<const f32x4*>(sp8 + cb + 16);

  __syncthreads();

  // ---- MFMA: acc[m][n] initialized with bias (C-in accumulates) ----
  f32x4 acc_in[4][2], acc_a[4][2];
#pragma unroll
  for (int m = 0; m < 4; ++m) {
    acc_in[m][0] = bi0; acc_in[m][1] = bi1;
    acc_a[m][0]  = ba0; acc_a[m][1]  = ba1;
  }

  // weight base pointers (imm offsets kk*64 B inside the loop)
  const unsigned short* wi0 = wTin + ((h * HDIM + wid * 32 + l15) * HDIM) + l4 * 8;
  const unsigned short* wi1 = wi0 + 16 * HDIM;
  const unsigned short* wa0 = wTa + ((h * HDIM + wid * 32 + l15) * HDIM) + l4 * 8;
  const unsigned short* wa1 = wa0 + 16 * HDIM;

  const int xsw = ((l15 & 7) << 4);   // per-thread swizzle bits (4..6)

#pragma unroll
  for (int kk = 0; kk < 4; ++kk) {
    bf16x8 xfr[4];
#pragma unroll
    for (int m = 0; m < 4; ++m) {
      int boff = ((m * 16 + l15) * 256 + kk * 64 + l4 * 16) ^ xsw;
      xfr[m] = *reinterpret_cast<const bf16x8*>(
          reinterpret_cast<const char*>(xs) + boff);
    }
    bf16x8 win[2], wa[2];
    win[0] = *reinterpret_cast<const bf16x8*>(wi0 + kk * 32);
    win[1] = *reinterpret_cast<const bf16x8*>(wi1 + kk * 32);
    wa[0]  = *reinterpret_cast<const bf16x8*>(wa0 + kk * 32);
    wa[1]  = *reinterpret_cast<const bf16x8*>(wa1 + kk * 32);
#pragma unroll
    for (int m = 0; m < 4; ++m)
#pragma unroll
      for (int n = 0; n < 2; ++n) {
        acc_in[m][n] = __builtin_amdgcn_mfma_f32_16x16x32_bf16(
            win[n], xfr[m], acc_in[m][n], 0, 0, 0);
        acc_a[m][n] = __builtin_amdgcn_mfma_f32_16x16x32_bf16(
            wa[n], xfr[m], acc_a[m][n], 0, 0, 0);
      }
  }

  // ---- epilogue ----
  // running row pointers (advance by 16 rows per m)
  const long base = (long)(rb * BM + l15) * WIDTH + cb;
  const float* ps = state + base;
  float*       po = out + base;
  const char* pxs = reinterpret_cast<const char*>(xs);
  // XOR applied after summing ALL low-order offsets (incl. n*32)
  const int xe0 = (l15 * 256 + (wid * 32 + l4 * 4) * 2) ^ xsw;        // n=0
  const int xe1 = (l15 * 256 + (wid * 32 + 16 + l4 * 4) * 2) ^ xsw;   // n=1

#pragma unroll
  for (int m = 0; m < 4; ++m) {
#pragma unroll
    for (int n = 0; n < 2; ++n) {
      f32x4 sv = *reinterpret_cast<const f32x4*>(ps + n * 16);
      u16x4 xb = *reinterpret_cast<const u16x4*>(
          pxs + (n ? xe1 : xe0) + m * 4096);
      f32x4 sp = n ? sp1 : sp0;
      f32x4 o;
#pragma unroll
      for (int r = 0; r < 4; ++r) {
        float gx  = __builtin_amdgcn_rcpf(1.0f + exp2f(-acc_in[m][n][r]));
        float ga  = __builtin_amdgcn_rcpf(1.0f + exp2f(-acc_a[m][n][r]));
        float av  = exp2f(-ga * sp[r]);
        float sc  = sqrtf(fmaxf(1.0f - av * av, 0.0f));
        o[r] = av * sv[r] + gx * bf2f(xb[r]) * sc;
      }
      *reinterpret_cast<f32x4*>(po + n * 16) = o;
    }
    ps += 16 * WIDTH;
    po += 16 * WIDTH;
  }
}

extern "C" void kernel_launch(void* const* d_in, const int* in_sizes, int n_in,
                              void* d_out, int out_size, void* d_ws, size_t ws_size,
                              hipStream_t stream) {
  const float* x       = (const float*)d_in[0];
  const float* state   = (const float*)d_in[1];
  const float* w_in    = (const float*)d_in[2];
  const float* b_in    = (const float*)d_in[3];
  const float* w_a     = (const float*)d_in[4];
  const float* b_a     = (const float*)d_in[5];
  const float* a_param = (const float*)d_in[6];
  float* out = (float*)d_out;

  unsigned short* wTin = (unsigned short*)d_ws;
  unsigned short* wTa  = wTin + NHEADS * HDIM * HDIM;
  float*          sp8  = (float*)(wTa + NHEADS * HDIM * HDIM);
  float*          sbi  = sp8 + WIDTH;
  float*          sba  = sbi + WIDTH;

  // prep: 16*128*128 = 262144 elements -> 1024 blocks
  hipLaunchKernelGGL(prep_kernel, dim3(1024), dim3(256), 0, stream,
                     w_in, w_a, a_param, b_in, b_a, wTin, wTa, sp8, sbi, sba);

  // main: (16384/64) row-blocks * 16 heads = 4096 blocks
  hipLaunchKernelGGL(rglru_kernel, dim3(4096), dim3(256), 0, stream,
                     x, state, sbi, sba, wTin, wTa, sp8, out);
}